// Round 10
// baseline (850.930 us; speedup 1.0000x reference)
//
#include <hip/hip_runtime.h>
#include <hip/hip_bf16.h>
#include <math.h>

#define N_NODES 50000
#define N_EDGES 800000
#define HID 128
#define OUT_DIM 40
#define BN_EPS 1e-5f

// ---------------------------------------------------------------------------
// degree count by dst (real edges only; +1 self-loop applied in dinv)
__global__ __launch_bounds__(256) void count_deg_kernel(const int* __restrict__ dst,
                                                        unsigned* __restrict__ deg, int E) {
    int e = blockIdx.x * blockDim.x + threadIdx.x;
    if (e < E) atomicAdd(&deg[dst[e]], 1u);
}

__global__ __launch_bounds__(256) void dinv_kernel(const unsigned* __restrict__ deg,
                                                   float* __restrict__ dinv, int n) {
    int v = blockIdx.x * blockDim.x + threadIdx.x;
    if (v < n) dinv[v] = rsqrtf((float)(deg[v] + 1u));
}

// ---------------------------------------------------------------------------
// CSR build: 3-kernel exclusive scan of deg -> rowptr, then bucket fill.
#define SCAN_CHUNK 1024

__global__ __launch_bounds__(256) void scan_partial_kernel(const unsigned* __restrict__ deg,
                                                           unsigned* __restrict__ bsum, int n) {
    __shared__ unsigned sd[256];
    int base = blockIdx.x * SCAN_CHUNK;
    unsigned s = 0;
    for (int i = threadIdx.x; i < SCAN_CHUNK; i += 256) {
        int idx = base + i;
        if (idx < n) s += deg[idx];
    }
    sd[threadIdx.x] = s;
    __syncthreads();
    for (int off = 128; off; off >>= 1) {
        if (threadIdx.x < off) sd[threadIdx.x] += sd[threadIdx.x + off];
        __syncthreads();
    }
    if (threadIdx.x == 0) bsum[blockIdx.x] = sd[0];
}

__global__ void scan_bsums_kernel(unsigned* __restrict__ bsum, int nb) {
    if (blockIdx.x == 0 && threadIdx.x == 0) {
        unsigned acc = 0;
        for (int i = 0; i < nb; ++i) { unsigned v = bsum[i]; bsum[i] = acc; acc += v; }
    }
}

__global__ __launch_bounds__(256) void scan_chunk_kernel(unsigned* __restrict__ deg,
                                                         const unsigned* __restrict__ bsum,
                                                         unsigned* __restrict__ rowptr, int n) {
    __shared__ unsigned ts[256];
    int base = blockIdx.x * SCAN_CHUNK;
    int i0 = base + threadIdx.x * 4;
    unsigned v[4]; unsigned s = 0;
#pragma unroll
    for (int j = 0; j < 4; ++j) {
        int idx = i0 + j;
        v[j] = (idx < n) ? deg[idx] : 0u;
        s += v[j];
    }
    ts[threadIdx.x] = s;
    __syncthreads();
    for (int off = 1; off < 256; off <<= 1) {
        unsigned add = (threadIdx.x >= (unsigned)off) ? ts[threadIdx.x - off] : 0u;
        __syncthreads();
        ts[threadIdx.x] += add;
        __syncthreads();
    }
    unsigned texcl = (threadIdx.x == 0) ? 0u : ts[threadIdx.x - 1];
    unsigned run = bsum[blockIdx.x] + texcl;
#pragma unroll
    for (int j = 0; j < 4; ++j) {
        int idx = i0 + j;
        if (idx < n) {
            rowptr[idx] = run;
            deg[idx] = run;          // cursor for csr_fill
            run += v[j];
            if (idx == n - 1) rowptr[n] = run;
        }
    }
}

// fill ecol + per-edge norm weight wts (CSR order): wts = dinv[src]*dinv[dst]
__global__ __launch_bounds__(256) void csr_fill_kernel(const int* __restrict__ src,
                                                       const int* __restrict__ dst,
                                                       const float* __restrict__ dinv,
                                                       unsigned* __restrict__ cursor,
                                                       int* __restrict__ ecol,
                                                       float* __restrict__ wts, int E) {
    int e = blockIdx.x * blockDim.x + threadIdx.x;
    if (e >= E) return;
    int s = src[e], d = dst[e];
    unsigned pos = atomicAdd(&cursor[d], 1u);
    ecol[pos] = s;
    wts[pos] = dinv[s] * dinv[d];
}

// ---------------------------------------------------------------------------
// h0 = alpha * x[:, :128] + beta * x[:, 128:]
__global__ __launch_bounds__(256) void init_h_kernel(const float* __restrict__ x,
                                                     const float* __restrict__ log_alpha,
                                                     const float* __restrict__ log_beta,
                                                     float* __restrict__ h, int n) {
    int gid = blockIdx.x * blockDim.x + threadIdx.x;
    if (gid >= n * HID) return;
    int v = gid >> 7, c = gid & 127;
    float alpha = expf(log_alpha[0]);
    float beta  = expf(log_beta[0]);
    const float* xr = x + (size_t)v * (2 * HID);
    h[gid] = alpha * xr[c] + beta * xr[HID + c];
}

// ---------------------------------------------------------------------------
// GEMM v2 (unchanged from round 8/9)
#define BM 64
__global__ __launch_bounds__(256) void gemm128_v2_kernel(const float* __restrict__ A,
                                                         const float* __restrict__ W,
                                                         const float* __restrict__ bias,
                                                         float* __restrict__ C,
                                                         int n, int do_relu) {
    __shared__ float As[BM][HID];  // 32 KB
    int row0 = blockIdx.x * BM;
    int nrow = min(BM, n - row0);
    {
        const float4* Ag = (const float4*)(A + (size_t)row0 * HID);
        float4* As4 = (float4*)&As[0][0];
        int n4 = nrow * (HID / 4);
        for (int i = threadIdx.x; i < n4; i += 256) As4[i] = Ag[i];
    }
    __syncthreads();

    int q  = threadIdx.x & 31;
    int rg = threadIdx.x >> 5;
    int r0 = rg * 8;
    const float4* W4 = (const float4*)W;

    float4 acc[8];
    float4 bv = make_float4(0.f, 0.f, 0.f, 0.f);
    if (bias) bv = ((const float4*)bias)[q];
#pragma unroll
    for (int i = 0; i < 8; ++i) acc[i] = bv;

#pragma unroll 4
    for (int k = 0; k < HID; ++k) {
        float4 w = W4[k * 32 + q];
#pragma unroll
        for (int i = 0; i < 8; ++i) {
            float a = As[r0 + i][k];
            acc[i].x = fmaf(a, w.x, acc[i].x);
            acc[i].y = fmaf(a, w.y, acc[i].y);
            acc[i].z = fmaf(a, w.z, acc[i].z);
            acc[i].w = fmaf(a, w.w, acc[i].w);
        }
    }

#pragma unroll
    for (int i = 0; i < 8; ++i) {
        int r = row0 + r0 + i;
        if (r < n) {
            float4 o = acc[i];
            if (do_relu) {
                o.x = fmaxf(o.x, 0.f); o.y = fmaxf(o.y, 0.f);
                o.z = fmaxf(o.z, 0.f); o.w = fmaxf(o.w, 0.f);
            }
            ((float4*)(C + (size_t)r * HID))[q] = o;
        }
    }
}

// ---------------------------------------------------------------------------
// agg v2: column-tiled CSR gather-reduce.
// blockIdx.y = column chunk (16 cols, 3.2 MB of m -> per-XCD L2-resident);
// x varies fastest in dispatch order so the GPU works chunk-by-chunk.
// Block = 256 threads = 16 nodes x 16 lanes; a 16-lane group reads a
// coalesced 64-B slice of m[src] per edge. wts precomputed in CSR order.
#define AGG_CHUNK 16
#define AGG_NODES 16
__global__ __launch_bounds__(256) void agg_csr_v2_kernel(const float* __restrict__ m,
                                                         const float* __restrict__ wts,
                                                         const float* __restrict__ dinv,
                                                         const float* __restrict__ conv_b,
                                                         const unsigned* __restrict__ rowptr,
                                                         const int* __restrict__ ecol,
                                                         float* __restrict__ out, int n) {
    int v = blockIdx.x * AGG_NODES + (threadIdx.x >> 4);
    if (v >= n) return;
    int c = blockIdx.y * AGG_CHUNK + (threadIdx.x & 15);
    float dv = dinv[v];
    float acc = conv_b[c] + m[(size_t)v * HID + c] * dv * dv;
    unsigned i   = rowptr[v];
    unsigned end = rowptr[v + 1];
    for (; i + 1 < end; i += 2) {
        int s0 = ecol[i], s1 = ecol[i + 1];
        float w0 = wts[i], w1 = wts[i + 1];
        acc = fmaf(w0, m[(size_t)s0 * HID + c], acc);
        acc = fmaf(w1, m[(size_t)s1 * HID + c], acc);
    }
    if (i < end) acc = fmaf(wts[i], m[(size_t)ecol[i] * HID + c], acc);
    out[(size_t)v * HID + c] = acc;
}

// ---------------------------------------------------------------------------
__global__ __launch_bounds__(256) void bn_stats_kernel(const float* __restrict__ h,
                                                       float* __restrict__ stats, int n) {
    int c = threadIdx.x & 127;
    int rt = (blockIdx.x * blockDim.x + threadIdx.x) >> 7;
    int rstride = (gridDim.x * blockDim.x) >> 7;
    float s = 0.0f, s2 = 0.0f;
    for (int r = rt; r < n; r += rstride) {
        float v = h[(size_t)r * HID + c];
        s += v; s2 += v * v;
    }
    atomicAdd(&stats[c], s);
    atomicAdd(&stats[HID + c], s2);
}

__global__ __launch_bounds__(256) void bn_apply_kernel(float* __restrict__ h,
                                                       const float* __restrict__ stats,
                                                       const float* __restrict__ gamma,
                                                       const float* __restrict__ beta,
                                                       int n) {
    int gid = blockIdx.x * blockDim.x + threadIdx.x;
    if (gid >= n * HID) return;
    int c = gid & 127;
    float inv_n = 1.0f / (float)n;
    float mean = stats[c] * inv_n;
    float var  = stats[HID + c] * inv_n - mean * mean;
    float sc = gamma[c] * rsqrtf(var + BN_EPS);
    float sh = beta[c] - mean * sc;
    h[gid] = fmaxf(h[gid] * sc + sh, 0.0f);
}

// ---------------------------------------------------------------------------
// final v2 (unchanged from round 9)
#define FB_ROWS 32
__global__ __launch_bounds__(256) void final_v2_kernel(const float* __restrict__ h,
                                                       const float* __restrict__ lw,
                                                       const float* __restrict__ lb,
                                                       float* __restrict__ out, int n) {
    __shared__ float lws[HID * OUT_DIM];  // 20 KB
    for (int i = threadIdx.x; i < HID * OUT_DIM; i += 256) lws[i] = lw[i];
    __syncthreads();

    int wave = threadIdx.x >> 6;
    int lane = threadIdx.x & 63;
    int rw   = lane >> 3;
    int sub  = lane & 7;
    int r = blockIdx.x * FB_ROWS + wave * 8 + rw;
    if (r >= n) return;

    int c0 = sub * 5;
    float acc[5];
#pragma unroll
    for (int i = 0; i < 5; ++i) acc[i] = lb[c0 + i];

    const float4* hr4 = (const float4*)(h + (size_t)r * HID);
#pragma unroll 4
    for (int k4 = 0; k4 < HID / 4; ++k4) {
        float4 hv = hr4[k4];
        int kb = k4 * 4;
#pragma unroll
        for (int j = 0; j < 4; ++j) {
            float a = (j == 0) ? hv.x : (j == 1) ? hv.y : (j == 2) ? hv.z : hv.w;
            const float* wr = &lws[(kb + j) * OUT_DIM + c0];
#pragma unroll
            for (int i = 0; i < 5; ++i) acc[i] = fmaf(a, wr[i], acc[i]);
        }
    }

    float mx = acc[0];
#pragma unroll
    for (int i = 1; i < 5; ++i) mx = fmaxf(mx, acc[i]);
    for (int off = 4; off; off >>= 1) mx = fmaxf(mx, __shfl_xor(mx, off));

    float s = 0.0f;
#pragma unroll
    for (int i = 0; i < 5; ++i) s += expf(acc[i] - mx);
    for (int off = 4; off; off >>= 1) s += __shfl_xor(s, off);
    float lse = mx + logf(s);

    float* orow = out + (size_t)r * OUT_DIM + c0;
#pragma unroll
    for (int i = 0; i < 5; ++i) orow[i] = acc[i] - lse;
}

// ---------------------------------------------------------------------------
extern "C" void kernel_launch(void* const* d_in, const int* in_sizes, int n_in,
                              void* d_out, int out_size, void* d_ws, size_t ws_size,
                              hipStream_t stream) {
    const float* x         = (const float*)d_in[0];
    const int*   ei        = (const int*)d_in[1];
    const float* log_alpha = (const float*)d_in[2];
    const float* log_beta  = (const float*)d_in[3];
    const float* mlp_w     = (const float*)d_in[4];
    const float* mlp_b     = (const float*)d_in[5];
    const float* conv_w    = (const float*)d_in[6];
    const float* conv_b    = (const float*)d_in[7];
    const float* bn_gamma  = (const float*)d_in[8];
    const float* bn_beta   = (const float*)d_in[9];
    const float* lin_w     = (const float*)d_in[10];
    const float* lin_b     = (const float*)d_in[11];
    float* out = (float*)d_out;

    const int n = N_NODES, E = N_EDGES;
    const int* src = ei;
    const int* dst = ei + E;

    // workspace layout (256B-aligned segments), total ~84 MB
    char* ws = (char*)d_ws;
    size_t off = 0;
    auto alloc = [&](size_t bytes) { char* p = ws + off; off += (bytes + 255) & ~(size_t)255; return p; };
    size_t hbytes = (size_t)n * HID * sizeof(float);        // 25.6 MB
    float*    hA     = (float*)alloc(hbytes);
    float*    hB     = (float*)alloc(hbytes);
    float*    hC     = (float*)alloc(hbytes);
    unsigned* rowptr = (unsigned*)alloc((size_t)(n + 1) * 4);
    unsigned* deg    = (unsigned*)alloc((size_t)n * 4);     // reused as cursor
    float*    dinv   = (float*)alloc((size_t)n * 4);
    int*      ecol   = (int*)alloc((size_t)E * 4);          // 3.2 MB
    float*    wts    = (float*)alloc((size_t)E * 4);        // 3.2 MB
    float*    stats  = (float*)alloc(512 * sizeof(float));
    unsigned* bsum   = (unsigned*)alloc(256 * 4);

    hipMemsetAsync(deg, 0, (size_t)n * 4, stream);
    hipMemsetAsync(stats, 0, 512 * sizeof(float), stream);

    const int B = 256;
    const int nscan = (n + SCAN_CHUNK - 1) / SCAN_CHUNK;   // 49
    count_deg_kernel<<<(E + B - 1) / B, B, 0, stream>>>(dst, deg, E);
    dinv_kernel<<<(n + B - 1) / B, B, 0, stream>>>(deg, dinv, n);
    scan_partial_kernel<<<nscan, B, 0, stream>>>(deg, bsum, n);
    scan_bsums_kernel<<<1, 64, 0, stream>>>(bsum, nscan);
    scan_chunk_kernel<<<nscan, B, 0, stream>>>(deg, bsum, rowptr, n);
    csr_fill_kernel<<<(E + B - 1) / B, B, 0, stream>>>(src, dst, dinv, deg, ecol, wts, E);

    init_h_kernel<<<(n * HID + B - 1) / B, B, 0, stream>>>(x, log_alpha, log_beta, hA, n);

    int gemm_grid = (n + BM - 1) / BM;
    int ngrid = (n * HID + B - 1) / B;
    dim3 agg_grid((n + AGG_NODES - 1) / AGG_NODES, HID / AGG_CHUNK);

    for (int i = 0; i < 3; ++i) {
        gemm128_v2_kernel<<<gemm_grid, B, 0, stream>>>(hA, mlp_w + (size_t)i * HID * HID,
                                                       mlp_b + (size_t)i * HID, hB, n, 1);
        gemm128_v2_kernel<<<gemm_grid, B, 0, stream>>>(hB, conv_w + (size_t)i * HID * HID,
                                                       nullptr, hC, n, 0);
        agg_csr_v2_kernel<<<agg_grid, B, 0, stream>>>(hC, wts, dinv, conv_b + (size_t)i * HID,
                                                      rowptr, ecol, hA, n);
        if (i < 2) {
            float* st = stats + (size_t)i * 256;
            bn_stats_kernel<<<512, B, 0, stream>>>(hA, st, n);
            bn_apply_kernel<<<ngrid, B, 0, stream>>>(hA, st, bn_gamma + (size_t)i * HID,
                                                     bn_beta + (size_t)i * HID, n);
        }
    }

    final_v2_kernel<<<(n + FB_ROWS - 1) / FB_ROWS, B, 0, stream>>>(hA, lin_w, lin_b, out, n);
}

// Round 11
// 772.362 us; speedup vs baseline: 1.1017x; 1.1017x over previous
//
#include <hip/hip_runtime.h>
#include <hip/hip_bf16.h>
#include <math.h>

#define N_NODES 50000
#define N_EDGES 800000
#define HID 128
#define OUT_DIM 40
#define BN_EPS 1e-5f

// ---------------------------------------------------------------------------
// degree count by dst (real edges only; +1 self-loop applied in dinv)
__global__ __launch_bounds__(256) void count_deg_kernel(const int* __restrict__ dst,
                                                        unsigned* __restrict__ deg, int E) {
    int e = blockIdx.x * blockDim.x + threadIdx.x;
    if (e < E) atomicAdd(&deg[dst[e]], 1u);
}

__global__ __launch_bounds__(256) void dinv_kernel(const unsigned* __restrict__ deg,
                                                   float* __restrict__ dinv, int n) {
    int v = blockIdx.x * blockDim.x + threadIdx.x;
    if (v < n) dinv[v] = rsqrtf((float)(deg[v] + 1u));
}

// ---------------------------------------------------------------------------
// CSR build: 3-kernel exclusive scan of deg -> rowptr, then bucket fill.
#define SCAN_CHUNK 1024

__global__ __launch_bounds__(256) void scan_partial_kernel(const unsigned* __restrict__ deg,
                                                           unsigned* __restrict__ bsum, int n) {
    __shared__ unsigned sd[256];
    int base = blockIdx.x * SCAN_CHUNK;
    unsigned s = 0;
    for (int i = threadIdx.x; i < SCAN_CHUNK; i += 256) {
        int idx = base + i;
        if (idx < n) s += deg[idx];
    }
    sd[threadIdx.x] = s;
    __syncthreads();
    for (int off = 128; off; off >>= 1) {
        if (threadIdx.x < off) sd[threadIdx.x] += sd[threadIdx.x + off];
        __syncthreads();
    }
    if (threadIdx.x == 0) bsum[blockIdx.x] = sd[0];
}

__global__ void scan_bsums_kernel(unsigned* __restrict__ bsum, int nb) {
    if (blockIdx.x == 0 && threadIdx.x == 0) {
        unsigned acc = 0;
        for (int i = 0; i < nb; ++i) { unsigned v = bsum[i]; bsum[i] = acc; acc += v; }
    }
}

__global__ __launch_bounds__(256) void scan_chunk_kernel(unsigned* __restrict__ deg,
                                                         const unsigned* __restrict__ bsum,
                                                         unsigned* __restrict__ rowptr, int n) {
    __shared__ unsigned ts[256];
    int base = blockIdx.x * SCAN_CHUNK;
    int i0 = base + threadIdx.x * 4;
    unsigned v[4]; unsigned s = 0;
#pragma unroll
    for (int j = 0; j < 4; ++j) {
        int idx = i0 + j;
        v[j] = (idx < n) ? deg[idx] : 0u;
        s += v[j];
    }
    ts[threadIdx.x] = s;
    __syncthreads();
    for (int off = 1; off < 256; off <<= 1) {
        unsigned add = (threadIdx.x >= (unsigned)off) ? ts[threadIdx.x - off] : 0u;
        __syncthreads();
        ts[threadIdx.x] += add;
        __syncthreads();
    }
    unsigned texcl = (threadIdx.x == 0) ? 0u : ts[threadIdx.x - 1];
    unsigned run = bsum[blockIdx.x] + texcl;
#pragma unroll
    for (int j = 0; j < 4; ++j) {
        int idx = i0 + j;
        if (idx < n) {
            rowptr[idx] = run;
            deg[idx] = run;          // cursor for csr_fill
            run += v[j];
            if (idx == n - 1) rowptr[n] = run;
        }
    }
}

// fill ecol + per-edge norm weight wts (CSR order): wts = dinv[src]*dinv[dst]
__global__ __launch_bounds__(256) void csr_fill_kernel(const int* __restrict__ src,
                                                       const int* __restrict__ dst,
                                                       const float* __restrict__ dinv,
                                                       unsigned* __restrict__ cursor,
                                                       int* __restrict__ ecol,
                                                       float* __restrict__ wts, int E) {
    int e = blockIdx.x * blockDim.x + threadIdx.x;
    if (e >= E) return;
    int s = src[e], d = dst[e];
    unsigned pos = atomicAdd(&cursor[d], 1u);
    ecol[pos] = s;
    wts[pos] = dinv[s] * dinv[d];
}

// ---------------------------------------------------------------------------
// h0 = alpha * x[:, :128] + beta * x[:, 128:]
__global__ __launch_bounds__(256) void init_h_kernel(const float* __restrict__ x,
                                                     const float* __restrict__ log_alpha,
                                                     const float* __restrict__ log_beta,
                                                     float* __restrict__ h, int n) {
    int gid = blockIdx.x * blockDim.x + threadIdx.x;
    if (gid >= n * HID) return;
    int v = gid >> 7, c = gid & 127;
    float alpha = expf(log_alpha[0]);
    float beta  = expf(log_beta[0]);
    const float* xr = x + (size_t)v * (2 * HID);
    h[gid] = alpha * xr[c] + beta * xr[HID + c];
}

// ---------------------------------------------------------------------------
// GEMM v3: C[n x 128] = act(A @ W + bias).
// A-tile stored TRANSPOSED in LDS: At[k][r] (32 KB). Thread = 4 rows x 8 cols:
// per k-step 1 ds_read_b128 (4 row-values, lanes rq=0..15 -> banks 4rq..4rq+3,
// 2 lanes/bank = conflict-free) + 2 w-float4 (L1/L2) + 32 FMA.
// Staging writes At[k][r] with lanes varying r -> 2-way, free.
#define BM 64
__global__ __launch_bounds__(256) void gemm128_v3_kernel(const float* __restrict__ A,
                                                         const float* __restrict__ W,
                                                         const float* __restrict__ bias,
                                                         float* __restrict__ C,
                                                         int n, int do_relu) {
    __shared__ float At[HID][BM];  // 32 KB, transposed tile
    int row0 = blockIdx.x * BM;
    int nrow = min(BM, n - row0);
    {
        int r   = threadIdx.x & 63;
        int k40 = threadIdx.x >> 6;   // 0..3
        if (r < nrow) {
            const float4* Ar = (const float4*)(A + (size_t)(row0 + r) * HID);
            for (int k4 = k40; k4 < HID / 4; k4 += 4) {
                float4 v = Ar[k4];
                At[k4 * 4 + 0][r] = v.x;
                At[k4 * 4 + 1][r] = v.y;
                At[k4 * 4 + 2][r] = v.z;
                At[k4 * 4 + 3][r] = v.w;
            }
        }
    }
    __syncthreads();

    int rq = threadIdx.x & 15;     // row quad: rows 4rq..4rq+3
    int cg = threadIdx.x >> 4;     // col group: cols 8cg..8cg+7
    int r0 = rq * 4;
    const float4* W4 = (const float4*)W;   // W4[k*32 + col/4]

    float4 acc[4][2];
    float4 b0 = make_float4(0.f, 0.f, 0.f, 0.f), b1 = b0;
    if (bias) { b0 = ((const float4*)bias)[cg * 2]; b1 = ((const float4*)bias)[cg * 2 + 1]; }
#pragma unroll
    for (int i = 0; i < 4; ++i) { acc[i][0] = b0; acc[i][1] = b1; }

#pragma unroll 4
    for (int k = 0; k < HID; ++k) {
        float4 a  = *(const float4*)&At[k][r0];
        float4 w0 = W4[k * 32 + cg * 2];
        float4 w1 = W4[k * 32 + cg * 2 + 1];
        float ar[4] = {a.x, a.y, a.z, a.w};
#pragma unroll
        for (int i = 0; i < 4; ++i) {
            acc[i][0].x = fmaf(ar[i], w0.x, acc[i][0].x);
            acc[i][0].y = fmaf(ar[i], w0.y, acc[i][0].y);
            acc[i][0].z = fmaf(ar[i], w0.z, acc[i][0].z);
            acc[i][0].w = fmaf(ar[i], w0.w, acc[i][0].w);
            acc[i][1].x = fmaf(ar[i], w1.x, acc[i][1].x);
            acc[i][1].y = fmaf(ar[i], w1.y, acc[i][1].y);
            acc[i][1].z = fmaf(ar[i], w1.z, acc[i][1].z);
            acc[i][1].w = fmaf(ar[i], w1.w, acc[i][1].w);
        }
    }

#pragma unroll
    for (int i = 0; i < 4; ++i) {
        int r = row0 + r0 + i;
        if (r < n) {
            float4 o0 = acc[i][0], o1 = acc[i][1];
            if (do_relu) {
                o0.x = fmaxf(o0.x, 0.f); o0.y = fmaxf(o0.y, 0.f);
                o0.z = fmaxf(o0.z, 0.f); o0.w = fmaxf(o0.w, 0.f);
                o1.x = fmaxf(o1.x, 0.f); o1.y = fmaxf(o1.y, 0.f);
                o1.z = fmaxf(o1.z, 0.f); o1.w = fmaxf(o1.w, 0.f);
            }
            float4* Cr = (float4*)(C + (size_t)r * HID + cg * 8);
            Cr[0] = o0; Cr[1] = o1;
        }
    }
}

// ---------------------------------------------------------------------------
// CSR aggregation (round-9 structure, measured 68 µs; wts precomputed):
// one 128-thread block per node.
__global__ __launch_bounds__(128) void agg_csr_kernel(const float* __restrict__ m,
                                                      const float* __restrict__ wts,
                                                      const float* __restrict__ dinv,
                                                      const float* __restrict__ conv_b,
                                                      const unsigned* __restrict__ rowptr,
                                                      const int* __restrict__ ecol,
                                                      float* __restrict__ out) {
    int v = blockIdx.x;
    int c = threadIdx.x;
    float dv = dinv[v];
    float acc = conv_b[c] + m[(size_t)v * HID + c] * dv * dv;
    unsigned i   = rowptr[v];
    unsigned end = rowptr[v + 1];
    for (; i + 1 < end; i += 2) {
        int s0 = ecol[i], s1 = ecol[i + 1];
        float w0 = wts[i], w1 = wts[i + 1];
        acc = fmaf(w0, m[(size_t)s0 * HID + c], acc);
        acc = fmaf(w1, m[(size_t)s1 * HID + c], acc);
    }
    if (i < end) acc = fmaf(wts[i], m[(size_t)ecol[i] * HID + c], acc);
    out[(size_t)v * HID + c] = acc;
}

// ---------------------------------------------------------------------------
__global__ __launch_bounds__(256) void bn_stats_kernel(const float* __restrict__ h,
                                                       float* __restrict__ stats, int n) {
    int c = threadIdx.x & 127;
    int rt = (blockIdx.x * blockDim.x + threadIdx.x) >> 7;
    int rstride = (gridDim.x * blockDim.x) >> 7;
    float s = 0.0f, s2 = 0.0f;
    for (int r = rt; r < n; r += rstride) {
        float v = h[(size_t)r * HID + c];
        s += v; s2 += v * v;
    }
    atomicAdd(&stats[c], s);
    atomicAdd(&stats[HID + c], s2);
}

__global__ __launch_bounds__(256) void bn_apply_kernel(float* __restrict__ h,
                                                       const float* __restrict__ stats,
                                                       const float* __restrict__ gamma,
                                                       const float* __restrict__ beta,
                                                       int n) {
    int gid = blockIdx.x * blockDim.x + threadIdx.x;
    if (gid >= n * HID) return;
    int c = gid & 127;
    float inv_n = 1.0f / (float)n;
    float mean = stats[c] * inv_n;
    float var  = stats[HID + c] * inv_n - mean * mean;
    float sc = gamma[c] * rsqrtf(var + BN_EPS);
    float sh = beta[c] - mean * sc;
    h[gid] = fmaxf(h[gid] * sc + sh, 0.0f);
}

// ---------------------------------------------------------------------------
// final v2 (unchanged)
#define FB_ROWS 32
__global__ __launch_bounds__(256) void final_v2_kernel(const float* __restrict__ h,
                                                       const float* __restrict__ lw,
                                                       const float* __restrict__ lb,
                                                       float* __restrict__ out, int n) {
    __shared__ float lws[HID * OUT_DIM];  // 20 KB
    for (int i = threadIdx.x; i < HID * OUT_DIM; i += 256) lws[i] = lw[i];
    __syncthreads();

    int wave = threadIdx.x >> 6;
    int lane = threadIdx.x & 63;
    int rw   = lane >> 3;
    int sub  = lane & 7;
    int r = blockIdx.x * FB_ROWS + wave * 8 + rw;
    if (r >= n) return;

    int c0 = sub * 5;
    float acc[5];
#pragma unroll
    for (int i = 0; i < 5; ++i) acc[i] = lb[c0 + i];

    const float4* hr4 = (const float4*)(h + (size_t)r * HID);
#pragma unroll 4
    for (int k4 = 0; k4 < HID / 4; ++k4) {
        float4 hv = hr4[k4];
        int kb = k4 * 4;
#pragma unroll
        for (int j = 0; j < 4; ++j) {
            float a = (j == 0) ? hv.x : (j == 1) ? hv.y : (j == 2) ? hv.z : hv.w;
            const float* wr = &lws[(kb + j) * OUT_DIM + c0];
#pragma unroll
            for (int i = 0; i < 5; ++i) acc[i] = fmaf(a, wr[i], acc[i]);
        }
    }

    float mx = acc[0];
#pragma unroll
    for (int i = 1; i < 5; ++i) mx = fmaxf(mx, acc[i]);
    for (int off = 4; off; off >>= 1) mx = fmaxf(mx, __shfl_xor(mx, off));

    float s = 0.0f;
#pragma unroll
    for (int i = 0; i < 5; ++i) s += expf(acc[i] - mx);
    for (int off = 4; off; off >>= 1) s += __shfl_xor(s, off);
    float lse = mx + logf(s);

    float* orow = out + (size_t)r * OUT_DIM + c0;
#pragma unroll
    for (int i = 0; i < 5; ++i) orow[i] = acc[i] - lse;
}

// ---------------------------------------------------------------------------
extern "C" void kernel_launch(void* const* d_in, const int* in_sizes, int n_in,
                              void* d_out, int out_size, void* d_ws, size_t ws_size,
                              hipStream_t stream) {
    const float* x         = (const float*)d_in[0];
    const int*   ei        = (const int*)d_in[1];
    const float* log_alpha = (const float*)d_in[2];
    const float* log_beta  = (const float*)d_in[3];
    const float* mlp_w     = (const float*)d_in[4];
    const float* mlp_b     = (const float*)d_in[5];
    const float* conv_w    = (const float*)d_in[6];
    const float* conv_b    = (const float*)d_in[7];
    const float* bn_gamma  = (const float*)d_in[8];
    const float* bn_beta   = (const float*)d_in[9];
    const float* lin_w     = (const float*)d_in[10];
    const float* lin_b     = (const float*)d_in[11];
    float* out = (float*)d_out;

    const int n = N_NODES, E = N_EDGES;
    const int* src = ei;
    const int* dst = ei + E;

    // workspace layout (256B-aligned segments), total ~84 MB
    char* ws = (char*)d_ws;
    size_t off = 0;
    auto alloc = [&](size_t bytes) { char* p = ws + off; off += (bytes + 255) & ~(size_t)255; return p; };
    size_t hbytes = (size_t)n * HID * sizeof(float);        // 25.6 MB
    float*    hA     = (float*)alloc(hbytes);
    float*    hB     = (float*)alloc(hbytes);
    float*    hC     = (float*)alloc(hbytes);
    unsigned* rowptr = (unsigned*)alloc((size_t)(n + 1) * 4);
    unsigned* deg    = (unsigned*)alloc((size_t)n * 4);     // reused as cursor
    float*    dinv   = (float*)alloc((size_t)n * 4);
    int*      ecol   = (int*)alloc((size_t)E * 4);          // 3.2 MB
    float*    wts    = (float*)alloc((size_t)E * 4);        // 3.2 MB
    float*    stats  = (float*)alloc(512 * sizeof(float));
    unsigned* bsum   = (unsigned*)alloc(256 * 4);

    hipMemsetAsync(deg, 0, (size_t)n * 4, stream);
    hipMemsetAsync(stats, 0, 512 * sizeof(float), stream);

    const int B = 256;
    const int nscan = (n + SCAN_CHUNK - 1) / SCAN_CHUNK;   // 49
    count_deg_kernel<<<(E + B - 1) / B, B, 0, stream>>>(dst, deg, E);
    dinv_kernel<<<(n + B - 1) / B, B, 0, stream>>>(deg, dinv, n);
    scan_partial_kernel<<<nscan, B, 0, stream>>>(deg, bsum, n);
    scan_bsums_kernel<<<1, 64, 0, stream>>>(bsum, nscan);
    scan_chunk_kernel<<<nscan, B, 0, stream>>>(deg, bsum, rowptr, n);
    csr_fill_kernel<<<(E + B - 1) / B, B, 0, stream>>>(src, dst, dinv, deg, ecol, wts, E);

    init_h_kernel<<<(n * HID + B - 1) / B, B, 0, stream>>>(x, log_alpha, log_beta, hA, n);

    int gemm_grid = (n + BM - 1) / BM;
    int ngrid = (n * HID + B - 1) / B;

    for (int i = 0; i < 3; ++i) {
        gemm128_v3_kernel<<<gemm_grid, B, 0, stream>>>(hA, mlp_w + (size_t)i * HID * HID,
                                                       mlp_b + (size_t)i * HID, hB, n, 1);
        gemm128_v3_kernel<<<gemm_grid, B, 0, stream>>>(hB, conv_w + (size_t)i * HID * HID,
                                                       nullptr, hC, n, 0);
        agg_csr_kernel<<<n, 128, 0, stream>>>(hC, wts, dinv, conv_b + (size_t)i * HID,
                                              rowptr, ecol, hA);
        if (i < 2) {
            float* st = stats + (size_t)i * 256;
            bn_stats_kernel<<<512, B, 0, stream>>>(hA, st, n);
            bn_apply_kernel<<<ngrid, B, 0, stream>>>(hA, st, bn_gamma + (size_t)i * HID,
                                                     bn_beta + (size_t)i * HID, n);
        }
    }

    final_v2_kernel<<<(n + FB_ROWS - 1) / FB_ROWS, B, 0, stream>>>(hA, lin_w, lin_b, out, n);
}

// Round 13
// 606.543 us; speedup vs baseline: 1.4029x; 1.2734x over previous
//
#include <hip/hip_runtime.h>
#include <hip/hip_bf16.h>
#include <math.h>

#define N_NODES 50000
#define N_EDGES 800000
#define HID 128
#define OUT_DIM 40
#define BN_EPS 1e-5f

typedef __attribute__((ext_vector_type(8))) short bf16x8;
typedef __attribute__((ext_vector_type(4))) float f32x4;

// f32 -> bf16 round-to-nearest-even
__device__ inline unsigned bfr(float f) {
    unsigned u = __float_as_uint(f);
    return (u + 0x7FFFu + ((u >> 16) & 1u)) >> 16;
}
__device__ inline unsigned pack2(float a, float b) { return bfr(a) | (bfr(b) << 16); }

// ---------------------------------------------------------------------------
// degree count by dst (real edges only; +1 self-loop applied in dinv)
__global__ __launch_bounds__(256) void count_deg_kernel(const int* __restrict__ dst,
                                                        unsigned* __restrict__ deg, int E) {
    int e = blockIdx.x * blockDim.x + threadIdx.x;
    if (e < E) atomicAdd(&deg[dst[e]], 1u);
}

__global__ __launch_bounds__(256) void dinv_kernel(const unsigned* __restrict__ deg,
                                                   float* __restrict__ dinv, int n) {
    int v = blockIdx.x * blockDim.x + threadIdx.x;
    if (v < n) dinv[v] = rsqrtf((float)(deg[v] + 1u));
}

// ---------------------------------------------------------------------------
// CSR build: 3-kernel exclusive scan of deg -> rowptr, then bucket fill.
#define SCAN_CHUNK 1024

__global__ __launch_bounds__(256) void scan_partial_kernel(const unsigned* __restrict__ deg,
                                                           unsigned* __restrict__ bsum, int n) {
    __shared__ unsigned sd[256];
    int base = blockIdx.x * SCAN_CHUNK;
    unsigned s = 0;
    for (int i = threadIdx.x; i < SCAN_CHUNK; i += 256) {
        int idx = base + i;
        if (idx < n) s += deg[idx];
    }
    sd[threadIdx.x] = s;
    __syncthreads();
    for (int off = 128; off; off >>= 1) {
        if (threadIdx.x < off) sd[threadIdx.x] += sd[threadIdx.x + off];
        __syncthreads();
    }
    if (threadIdx.x == 0) bsum[blockIdx.x] = sd[0];
}

__global__ void scan_bsums_kernel(unsigned* __restrict__ bsum, int nb) {
    if (blockIdx.x == 0 && threadIdx.x == 0) {
        unsigned acc = 0;
        for (int i = 0; i < nb; ++i) { unsigned v = bsum[i]; bsum[i] = acc; acc += v; }
    }
}

__global__ __launch_bounds__(256) void scan_chunk_kernel(unsigned* __restrict__ deg,
                                                         const unsigned* __restrict__ bsum,
                                                         unsigned* __restrict__ rowptr, int n) {
    __shared__ unsigned ts[256];
    int base = blockIdx.x * SCAN_CHUNK;
    int i0 = base + threadIdx.x * 4;
    unsigned v[4]; unsigned s = 0;
#pragma unroll
    for (int j = 0; j < 4; ++j) {
        int idx = i0 + j;
        v[j] = (idx < n) ? deg[idx] : 0u;
        s += v[j];
    }
    ts[threadIdx.x] = s;
    __syncthreads();
    for (int off = 1; off < 256; off <<= 1) {
        unsigned add = (threadIdx.x >= (unsigned)off) ? ts[threadIdx.x - off] : 0u;
        __syncthreads();
        ts[threadIdx.x] += add;
        __syncthreads();
    }
    unsigned texcl = (threadIdx.x == 0) ? 0u : ts[threadIdx.x - 1];
    unsigned run = bsum[blockIdx.x] + texcl;
#pragma unroll
    for (int j = 0; j < 4; ++j) {
        int idx = i0 + j;
        if (idx < n) {
            rowptr[idx] = run;
            deg[idx] = run;          // cursor for csr_fill
            run += v[j];
            if (idx == n - 1) rowptr[n] = run;
        }
    }
}

// fill ecol + per-edge norm weight wts (CSR order): wts = dinv[src]*dinv[dst]
__global__ __launch_bounds__(256) void csr_fill_kernel(const int* __restrict__ src,
                                                       const int* __restrict__ dst,
                                                       const float* __restrict__ dinv,
                                                       unsigned* __restrict__ cursor,
                                                       int* __restrict__ ecol,
                                                       float* __restrict__ wts, int E) {
    int e = blockIdx.x * blockDim.x + threadIdx.x;
    if (e >= E) return;
    int s = src[e], d = dst[e];
    unsigned pos = atomicAdd(&cursor[d], 1u);
    ecol[pos] = s;
    wts[pos] = dinv[s] * dinv[d];
}

// ---------------------------------------------------------------------------
// h0 = alpha * x[:, :128] + beta * x[:, 128:]
__global__ __launch_bounds__(256) void init_h_kernel(const float* __restrict__ x,
                                                     const float* __restrict__ log_alpha,
                                                     const float* __restrict__ log_beta,
                                                     float* __restrict__ h, int n) {
    int gid = blockIdx.x * blockDim.x + threadIdx.x;
    if (gid >= n * HID) return;
    int v = gid >> 7, c = gid & 127;
    float alpha = expf(log_alpha[0]);
    float beta  = expf(log_beta[0]);
    const float* xr = x + (size_t)v * (2 * HID);
    h[gid] = alpha * xr[c] + beta * xr[HID + c];
}

// ---------------------------------------------------------------------------
// GEMM v4 (bf16 MFMA): C[n x 128] = act(A @ W + bias), fp32 in/out, bf16 compute.
// Block = 256 thr (4 waves, 2x2 of 64x64), tile 128 rows x 128 cols x K=128.
// A (bf16, [r][k]) and W^T (bf16, [c][k]) staged in LDS (32+32 KB -> 2 blk/CU)
// with XOR swizzle byte ^= (row&7)<<4 on BOTH write and read (G4; reg-staged).
// mfma_f32_16x16x32_bf16: A row=lane&15,k=(lane>>4)*8+j; C col=lane&15,
// row=(lane>>4)*4+reg (m89-verified). fp32 accumulate.
#define GBM 128
__global__ __launch_bounds__(256) void gemm128_bf16_kernel(const float* __restrict__ A,
                                                           const float* __restrict__ W,
                                                           const float* __restrict__ bias,
                                                           float* __restrict__ C,
                                                           int n, int do_relu) {
    __shared__ short As[GBM * HID];   // 32 KB: [r][k] bf16, pitch 256 B
    __shared__ short Ws[HID * HID];   // 32 KB: [c][k] bf16 (W transposed)

    int row0 = blockIdx.x * GBM;
    int nrow = min(GBM, n - row0);

    // stage A (fp32 -> bf16), swizzled; pad rows = 0
    {
        const float4* A4 = (const float4*)(A + (size_t)row0 * HID);
        for (int idx = threadIdx.x; idx < GBM * 32; idx += 256) {
            int r = idx >> 5, k4 = idx & 31;
            uint2 val = make_uint2(0u, 0u);
            if (r < nrow) {
                float4 v = A4[r * 32 + k4];
                val.x = pack2(v.x, v.y);
                val.y = pack2(v.z, v.w);
            }
            int byte = (r * 256 + k4 * 8) ^ ((r & 7) << 4);
            *(uint2*)((char*)As + byte) = val;
        }
    }
    // stage W transposed (fp32 [k][c] -> bf16 [c][k]), swizzled
    {
        const float4* W4 = (const float4*)W;
        for (int idx = threadIdx.x; idx < 1024; idx += 256) {
            int kb = idx >> 5;           // k0 = kb*4
            int cb = idx & 31;           // c0 = cb*4
            float4 w0 = W4[(kb * 4 + 0) * 32 + cb];
            float4 w1 = W4[(kb * 4 + 1) * 32 + cb];
            float4 w2 = W4[(kb * 4 + 2) * 32 + cb];
            float4 w3 = W4[(kb * 4 + 3) * 32 + cb];
            float cols[4][4] = {{w0.x, w1.x, w2.x, w3.x},
                                {w0.y, w1.y, w2.y, w3.y},
                                {w0.z, w1.z, w2.z, w3.z},
                                {w0.w, w1.w, w2.w, w3.w}};
#pragma unroll
            for (int ci = 0; ci < 4; ++ci) {
                int c = cb * 4 + ci;
                uint2 val;
                val.x = pack2(cols[ci][0], cols[ci][1]);
                val.y = pack2(cols[ci][2], cols[ci][3]);
                int byte = (c * 256 + kb * 8) ^ ((c & 7) << 4);
                *(uint2*)((char*)Ws + byte) = val;
            }
        }
    }
    __syncthreads();

    int wv   = threadIdx.x >> 6;
    int lane = threadIdx.x & 63;
    int wr = wv >> 1, wc = wv & 1;
    int lr = lane & 15, lg = lane >> 4;

    f32x4 acc[4][4];
#pragma unroll
    for (int nf = 0; nf < 4; ++nf) {
        float bv = bias ? bias[wc * 64 + nf * 16 + lr] : 0.0f;
#pragma unroll
        for (int m = 0; m < 4; ++m) acc[m][nf] = (f32x4){bv, bv, bv, bv};
    }

#pragma unroll
    for (int ks = 0; ks < 4; ++ks) {
        int kbyte = ks * 64 + lg * 16;
        bf16x8 af[4], bfv[4];
#pragma unroll
        for (int m = 0; m < 4; ++m) {
            int row = wr * 64 + m * 16 + lr;
            int byte = (row * 256 + kbyte) ^ ((row & 7) << 4);
            af[m] = *(const bf16x8*)((const char*)As + byte);
        }
#pragma unroll
        for (int nf = 0; nf < 4; ++nf) {
            int col = wc * 64 + nf * 16 + lr;
            int byte = (col * 256 + kbyte) ^ ((col & 7) << 4);
            bfv[nf] = *(const bf16x8*)((const char*)Ws + byte);
        }
#pragma unroll
        for (int m = 0; m < 4; ++m)
#pragma unroll
            for (int nf = 0; nf < 4; ++nf)
                acc[m][nf] = __builtin_amdgcn_mfma_f32_16x16x32_bf16(af[m], bfv[nf],
                                                                     acc[m][nf], 0, 0, 0);
    }

#pragma unroll
    for (int m = 0; m < 4; ++m) {
#pragma unroll
        for (int nf = 0; nf < 4; ++nf) {
            int col = wc * 64 + nf * 16 + lr;
#pragma unroll
            for (int reg = 0; reg < 4; ++reg) {
                int row = row0 + wr * 64 + m * 16 + lg * 4 + reg;
                if (row < n) {
                    float v = acc[m][nf][reg];
                    if (do_relu) v = fmaxf(v, 0.0f);
                    C[(size_t)row * HID + col] = v;
                }
            }
        }
    }
}

// ---------------------------------------------------------------------------
// CSR aggregation (round-9 structure, measured 66 µs): one 128-thr block/node.
__global__ __launch_bounds__(128) void agg_csr_kernel(const float* __restrict__ m,
                                                      const float* __restrict__ wts,
                                                      const float* __restrict__ dinv,
                                                      const float* __restrict__ conv_b,
                                                      const unsigned* __restrict__ rowptr,
                                                      const int* __restrict__ ecol,
                                                      float* __restrict__ out) {
    int v = blockIdx.x;
    int c = threadIdx.x;
    float dv = dinv[v];
    float acc = conv_b[c] + m[(size_t)v * HID + c] * dv * dv;
    unsigned i   = rowptr[v];
    unsigned end = rowptr[v + 1];
    for (; i + 1 < end; i += 2) {
        int s0 = ecol[i], s1 = ecol[i + 1];
        float w0 = wts[i], w1 = wts[i + 1];
        acc = fmaf(w0, m[(size_t)s0 * HID + c], acc);
        acc = fmaf(w1, m[(size_t)s1 * HID + c], acc);
    }
    if (i < end) acc = fmaf(wts[i], m[(size_t)ecol[i] * HID + c], acc);
    out[(size_t)v * HID + c] = acc;
}

// ---------------------------------------------------------------------------
__global__ __launch_bounds__(256) void bn_stats_kernel(const float* __restrict__ h,
                                                       float* __restrict__ stats, int n) {
    int c = threadIdx.x & 127;
    int rt = (blockIdx.x * blockDim.x + threadIdx.x) >> 7;
    int rstride = (gridDim.x * blockDim.x) >> 7;
    float s = 0.0f, s2 = 0.0f;
    for (int r = rt; r < n; r += rstride) {
        float v = h[(size_t)r * HID + c];
        s += v; s2 += v * v;
    }
    atomicAdd(&stats[c], s);
    atomicAdd(&stats[HID + c], s2);
}

__global__ __launch_bounds__(256) void bn_apply_kernel(float* __restrict__ h,
                                                       const float* __restrict__ stats,
                                                       const float* __restrict__ gamma,
                                                       const float* __restrict__ beta,
                                                       int n) {
    int gid = blockIdx.x * blockDim.x + threadIdx.x;
    if (gid >= n * HID) return;
    int c = gid & 127;
    float inv_n = 1.0f / (float)n;
    float mean = stats[c] * inv_n;
    float var  = stats[HID + c] * inv_n - mean * mean;
    float sc = gamma[c] * rsqrtf(var + BN_EPS);
    float sh = beta[c] - mean * sc;
    h[gid] = fmaxf(h[gid] * sc + sh, 0.0f);
}

// ---------------------------------------------------------------------------
// final v2 (unchanged)
#define FB_ROWS 32
__global__ __launch_bounds__(256) void final_v2_kernel(const float* __restrict__ h,
                                                       const float* __restrict__ lw,
                                                       const float* __restrict__ lb,
                                                       float* __restrict__ out, int n) {
    __shared__ float lws[HID * OUT_DIM];  // 20 KB
    for (int i = threadIdx.x; i < HID * OUT_DIM; i += 256) lws[i] = lw[i];
    __syncthreads();

    int wave = threadIdx.x >> 6;
    int lane = threadIdx.x & 63;
    int rw   = lane >> 3;
    int sub  = lane & 7;
    int r = blockIdx.x * FB_ROWS + wave * 8 + rw;
    if (r >= n) return;

    int c0 = sub * 5;
    float acc[5];
#pragma unroll
    for (int i = 0; i < 5; ++i) acc[i] = lb[c0 + i];

    const float4* hr4 = (const float4*)(h + (size_t)r * HID);
#pragma unroll 4
    for (int k4 = 0; k4 < HID / 4; ++k4) {
        float4 hv = hr4[k4];
        int kb = k4 * 4;
#pragma unroll
        for (int j = 0; j < 4; ++j) {
            float a = (j == 0) ? hv.x : (j == 1) ? hv.y : (j == 2) ? hv.z : hv.w;
            const float* wr2 = &lws[(kb + j) * OUT_DIM + c0];
#pragma unroll
            for (int i = 0; i < 5; ++i) acc[i] = fmaf(a, wr2[i], acc[i]);
        }
    }

    float mx = acc[0];
#pragma unroll
    for (int i = 1; i < 5; ++i) mx = fmaxf(mx, acc[i]);
    for (int off = 4; off; off >>= 1) mx = fmaxf(mx, __shfl_xor(mx, off));

    float s = 0.0f;
#pragma unroll
    for (int i = 0; i < 5; ++i) s += expf(acc[i] - mx);
    for (int off = 4; off; off >>= 1) s += __shfl_xor(s, off);
    float lse = mx + logf(s);

    float* orow = out + (size_t)r * OUT_DIM + c0;
#pragma unroll
    for (int i = 0; i < 5; ++i) orow[i] = acc[i] - lse;
}

// ---------------------------------------------------------------------------
extern "C" void kernel_launch(void* const* d_in, const int* in_sizes, int n_in,
                              void* d_out, int out_size, void* d_ws, size_t ws_size,
                              hipStream_t stream) {
    const float* x         = (const float*)d_in[0];
    const int*   ei        = (const int*)d_in[1];
    const float* log_alpha = (const float*)d_in[2];
    const float* log_beta  = (const float*)d_in[3];
    const float* mlp_w     = (const float*)d_in[4];
    const float* mlp_b     = (const float*)d_in[5];
    const float* conv_w    = (const float*)d_in[6];
    const float* conv_b    = (const float*)d_in[7];
    const float* bn_gamma  = (const float*)d_in[8];
    const float* bn_beta   = (const float*)d_in[9];
    const float* lin_w     = (const float*)d_in[10];
    const float* lin_b     = (const float*)d_in[11];
    float* out = (float*)d_out;

    const int n = N_NODES, E = N_EDGES;
    const int* src = ei;
    const int* dst = ei + E;

    // workspace layout (256B-aligned segments), total ~84 MB
    char* ws = (char*)d_ws;
    size_t off = 0;
    auto alloc = [&](size_t bytes) { char* p = ws + off; off += (bytes + 255) & ~(size_t)255; return p; };
    size_t hbytes = (size_t)n * HID * sizeof(float);        // 25.6 MB
    float*    hA     = (float*)alloc(hbytes);
    float*    hB     = (float*)alloc(hbytes);
    float*    hC     = (float*)alloc(hbytes);
    unsigned* rowptr = (unsigned*)alloc((size_t)(n + 1) * 4);
    unsigned* deg    = (unsigned*)alloc((size_t)n * 4);     // reused as cursor
    float*    dinv   = (float*)alloc((size_t)n * 4);
    int*      ecol   = (int*)alloc((size_t)E * 4);          // 3.2 MB
    float*    wts    = (float*)alloc((size_t)E * 4);        // 3.2 MB
    float*    stats  = (float*)alloc(512 * sizeof(float));
    unsigned* bsum   = (unsigned*)alloc(256 * 4);

    hipMemsetAsync(deg, 0, (size_t)n * 4, stream);
    hipMemsetAsync(stats, 0, 512 * sizeof(float), stream);

    const int B = 256;
    const int nscan = (n + SCAN_CHUNK - 1) / SCAN_CHUNK;   // 49
    count_deg_kernel<<<(E + B - 1) / B, B, 0, stream>>>(dst, deg, E);
    dinv_kernel<<<(n + B - 1) / B, B, 0, stream>>>(deg, dinv, n);
    scan_partial_kernel<<<nscan, B, 0, stream>>>(deg, bsum, n);
    scan_bsums_kernel<<<1, 64, 0, stream>>>(bsum, nscan);
    scan_chunk_kernel<<<nscan, B, 0, stream>>>(deg, bsum, rowptr, n);
    csr_fill_kernel<<<(E + B - 1) / B, B, 0, stream>>>(src, dst, dinv, deg, ecol, wts, E);

    init_h_kernel<<<(n * HID + B - 1) / B, B, 0, stream>>>(x, log_alpha, log_beta, hA, n);

    int gemm_grid = (n + GBM - 1) / GBM;
    int ngrid = (n * HID + B - 1) / B;

    for (int i = 0; i < 3; ++i) {
        gemm128_bf16_kernel<<<gemm_grid, B, 0, stream>>>(hA, mlp_w + (size_t)i * HID * HID,
                                                         mlp_b + (size_t)i * HID, hB, n, 1);
        gemm128_bf16_kernel<<<gemm_grid, B, 0, stream>>>(hB, conv_w + (size_t)i * HID * HID,
                                                         nullptr, hC, n, 0);
        agg_csr_kernel<<<n, 128, 0, stream>>>(hC, wts, dinv, conv_b + (size_t)i * HID,
                                              rowptr, ecol, hA);
        if (i < 2) {
            float* st = stats + (size_t)i * 256;
            bn_stats_kernel<<<512, B, 0, stream>>>(hA, st, n);
            bn_apply_kernel<<<ngrid, B, 0, stream>>>(hA, st, bn_gamma + (size_t)i * HID,
                                                     bn_beta + (size_t)i * HID, n);
        }
    }

    final_v2_kernel<<<(n + FB_ROWS - 1) / FB_ROWS, B, 0, stream>>>(hA, lin_w, lin_b, out, n);
}

// Round 14
// 580.332 us; speedup vs baseline: 1.4663x; 1.0452x over previous
//
#include <hip/hip_runtime.h>
#include <hip/hip_bf16.h>
#include <math.h>

#define N_NODES 50000
#define N_EDGES 800000
#define HID 128
#define OUT_DIM 40
#define BN_EPS 1e-5f

typedef __attribute__((ext_vector_type(8))) short bf16x8;
typedef __attribute__((ext_vector_type(4))) float f32x4;

// f32 -> bf16 round-to-nearest-even (bit pattern in low 16)
__device__ inline unsigned bfr(float f) {
    unsigned u = __float_as_uint(f);
    return (u + 0x7FFFu + ((u >> 16) & 1u)) >> 16;
}
__device__ inline unsigned pack2(float a, float b) { return bfr(a) | (bfr(b) << 16); }
__device__ inline float b2f(unsigned short u) { return __uint_as_float((unsigned)u << 16); }

// ---------------------------------------------------------------------------
// degree count by dst (real edges only; +1 self-loop applied in dinv)
__global__ __launch_bounds__(256) void count_deg_kernel(const int* __restrict__ dst,
                                                        unsigned* __restrict__ deg, int E) {
    int e = blockIdx.x * blockDim.x + threadIdx.x;
    if (e < E) atomicAdd(&deg[dst[e]], 1u);
}

__global__ __launch_bounds__(256) void dinv_kernel(const unsigned* __restrict__ deg,
                                                   float* __restrict__ dinv, int n) {
    int v = blockIdx.x * blockDim.x + threadIdx.x;
    if (v < n) dinv[v] = rsqrtf((float)(deg[v] + 1u));
}

// ---------------------------------------------------------------------------
// CSR build: 3-kernel exclusive scan of deg -> rowptr, then bucket fill.
#define SCAN_CHUNK 1024

__global__ __launch_bounds__(256) void scan_partial_kernel(const unsigned* __restrict__ deg,
                                                           unsigned* __restrict__ bsum, int n) {
    __shared__ unsigned sd[256];
    int base = blockIdx.x * SCAN_CHUNK;
    unsigned s = 0;
    for (int i = threadIdx.x; i < SCAN_CHUNK; i += 256) {
        int idx = base + i;
        if (idx < n) s += deg[idx];
    }
    sd[threadIdx.x] = s;
    __syncthreads();
    for (int off = 128; off; off >>= 1) {
        if (threadIdx.x < off) sd[threadIdx.x] += sd[threadIdx.x + off];
        __syncthreads();
    }
    if (threadIdx.x == 0) bsum[blockIdx.x] = sd[0];
}

__global__ void scan_bsums_kernel(unsigned* __restrict__ bsum, int nb) {
    if (blockIdx.x == 0 && threadIdx.x == 0) {
        unsigned acc = 0;
        for (int i = 0; i < nb; ++i) { unsigned v = bsum[i]; bsum[i] = acc; acc += v; }
    }
}

__global__ __launch_bounds__(256) void scan_chunk_kernel(unsigned* __restrict__ deg,
                                                         const unsigned* __restrict__ bsum,
                                                         unsigned* __restrict__ rowptr, int n) {
    __shared__ unsigned ts[256];
    int base = blockIdx.x * SCAN_CHUNK;
    int i0 = base + threadIdx.x * 4;
    unsigned v[4]; unsigned s = 0;
#pragma unroll
    for (int j = 0; j < 4; ++j) {
        int idx = i0 + j;
        v[j] = (idx < n) ? deg[idx] : 0u;
        s += v[j];
    }
    ts[threadIdx.x] = s;
    __syncthreads();
    for (int off = 1; off < 256; off <<= 1) {
        unsigned add = (threadIdx.x >= (unsigned)off) ? ts[threadIdx.x - off] : 0u;
        __syncthreads();
        ts[threadIdx.x] += add;
        __syncthreads();
    }
    unsigned texcl = (threadIdx.x == 0) ? 0u : ts[threadIdx.x - 1];
    unsigned run = bsum[blockIdx.x] + texcl;
#pragma unroll
    for (int j = 0; j < 4; ++j) {
        int idx = i0 + j;
        if (idx < n) {
            rowptr[idx] = run;
            deg[idx] = run;          // cursor for csr_fill
            run += v[j];
            if (idx == n - 1) rowptr[n] = run;
        }
    }
}

// fill ecol + per-edge norm weight wts (CSR order): wts = dinv[src]*dinv[dst]
__global__ __launch_bounds__(256) void csr_fill_kernel(const int* __restrict__ src,
                                                       const int* __restrict__ dst,
                                                       const float* __restrict__ dinv,
                                                       unsigned* __restrict__ cursor,
                                                       int* __restrict__ ecol,
                                                       float* __restrict__ wts, int E) {
    int e = blockIdx.x * blockDim.x + threadIdx.x;
    if (e >= E) return;
    int s = src[e], d = dst[e];
    unsigned pos = atomicAdd(&cursor[d], 1u);
    ecol[pos] = s;
    wts[pos] = dinv[s] * dinv[d];
}

// ---------------------------------------------------------------------------
// h0 = alpha * x[:, :128] + beta * x[:, 128:]  (f32)
__global__ __launch_bounds__(256) void init_h_kernel(const float* __restrict__ x,
                                                     const float* __restrict__ log_alpha,
                                                     const float* __restrict__ log_beta,
                                                     float* __restrict__ h, int n) {
    int gid = blockIdx.x * blockDim.x + threadIdx.x;
    if (gid >= n * HID) return;
    int v = gid >> 7, c = gid & 127;
    float alpha = expf(log_alpha[0]);
    float beta  = expf(log_beta[0]);
    const float* xr = x + (size_t)v * (2 * HID);
    h[gid] = alpha * xr[c] + beta * xr[HID + c];
}

// ---------------------------------------------------------------------------
// W precast: 6 matrices (mlp 0..2, conv 0..2) -> bf16 [c][k], swizzled 32 KB
// LDS images. wbf[b] for b = 2*layer + (0=mlp, 1=conv). Runs once per launch.
__global__ __launch_bounds__(256) void wcast_kernel(const float* __restrict__ mlp_w,
                                                    const float* __restrict__ conv_w,
                                                    char* __restrict__ wbf) {
    int b = blockIdx.x;  // 0..5
    const float* W = (b & 1) ? conv_w + (size_t)(b >> 1) * HID * HID
                             : mlp_w + (size_t)(b >> 1) * HID * HID;
    char* dst = wbf + (size_t)b * 32768;
    const float4* W4 = (const float4*)W;
    for (int idx = threadIdx.x; idx < 1024; idx += 256) {
        int kb = idx >> 5;           // k block of 4
        int cb = idx & 31;           // c block of 4
        float4 w0 = W4[(kb * 4 + 0) * 32 + cb];
        float4 w1 = W4[(kb * 4 + 1) * 32 + cb];
        float4 w2 = W4[(kb * 4 + 2) * 32 + cb];
        float4 w3 = W4[(kb * 4 + 3) * 32 + cb];
        float cols[4][4] = {{w0.x, w1.x, w2.x, w3.x},
                            {w0.y, w1.y, w2.y, w3.y},
                            {w0.z, w1.z, w2.z, w3.z},
                            {w0.w, w1.w, w2.w, w3.w}};
#pragma unroll
        for (int ci = 0; ci < 4; ++ci) {
            int c = cb * 4 + ci;
            uint2 val;
            val.x = pack2(cols[ci][0], cols[ci][1]);
            val.y = pack2(cols[ci][2], cols[ci][3]);
            int byte = (c * 256 + kb * 8) ^ ((c & 7) << 4);
            *(uint2*)(dst + byte) = val;
        }
    }
}

// ---------------------------------------------------------------------------
// Shared MFMA core. LDS: As (bf16 [r][k], swizzled), Ws (bf16 [c][k], swizzled).
// mfma_f32_16x16x32_bf16; fragment/layout per m89-verified mappings.
#define GBM 128

__device__ inline void gemm_mfma_core(const short* As, const short* Ws,
                                      const float* bias, f32x4 acc[4][4]) {
    int wv   = threadIdx.x >> 6;
    int lane = threadIdx.x & 63;
    int wr = wv >> 1, wc = wv & 1;
    int lr = lane & 15, lg = lane >> 4;

#pragma unroll
    for (int nf = 0; nf < 4; ++nf) {
        float bv = bias ? bias[wc * 64 + nf * 16 + lr] : 0.0f;
#pragma unroll
        for (int m = 0; m < 4; ++m) acc[m][nf] = (f32x4){bv, bv, bv, bv};
    }

#pragma unroll
    for (int ks = 0; ks < 4; ++ks) {
        int kbyte = ks * 64 + lg * 16;
        bf16x8 af[4], bfv[4];
#pragma unroll
        for (int m = 0; m < 4; ++m) {
            int row = wr * 64 + m * 16 + lr;
            int byte = (row * 256 + kbyte) ^ ((row & 7) << 4);
            af[m] = *(const bf16x8*)((const char*)As + byte);
        }
#pragma unroll
        for (int nf = 0; nf < 4; ++nf) {
            int col = wc * 64 + nf * 16 + lr;
            int byte = (col * 256 + kbyte) ^ ((col & 7) << 4);
            bfv[nf] = *(const bf16x8*)((const char*)Ws + byte);
        }
#pragma unroll
        for (int m = 0; m < 4; ++m)
#pragma unroll
            for (int nf = 0; nf < 4; ++nf)
                acc[m][nf] = __builtin_amdgcn_mfma_f32_16x16x32_bf16(af[m], bfv[nf],
                                                                     acc[m][nf], 0, 0, 0);
    }
}

// MLP gemm: A f32 (convert-stage), W precast image, out bf16, +bias +relu
__global__ __launch_bounds__(256) void gemm_mlp_kernel(const float* __restrict__ A,
                                                       const char* __restrict__ Wimg,
                                                       const float* __restrict__ bias,
                                                       unsigned short* __restrict__ Cb,
                                                       int n) {
    __shared__ short As[GBM * HID];   // 32 KB
    __shared__ short Ws[HID * HID];   // 32 KB

    int row0 = blockIdx.x * GBM;
    int nrow = min(GBM, n - row0);

    {   // stage A: f32 -> bf16, swizzled
        const float4* A4 = (const float4*)(A + (size_t)row0 * HID);
        for (int idx = threadIdx.x; idx < GBM * 32; idx += 256) {
            int r = idx >> 5, k4 = idx & 31;
            uint2 val = make_uint2(0u, 0u);
            if (r < nrow) {
                float4 v = A4[r * 32 + k4];
                val.x = pack2(v.x, v.y);
                val.y = pack2(v.z, v.w);
            }
            int byte = (r * 256 + k4 * 8) ^ ((r & 7) << 4);
            *(uint2*)((char*)As + byte) = val;
        }
    }
    {   // stage W: straight 32 KB copy (already bf16 + swizzled)
        const uint4* Wg = (const uint4*)Wimg;
        uint4* Wl = (uint4*)Ws;
        for (int i = threadIdx.x; i < 2048; i += 256) Wl[i] = Wg[i];
    }
    __syncthreads();

    f32x4 acc[4][4];
    gemm_mfma_core(As, Ws, bias, acc);

    int wv   = threadIdx.x >> 6;
    int lane = threadIdx.x & 63;
    int wr = wv >> 1, wc = wv & 1;
    int lr = lane & 15, lg = lane >> 4;
#pragma unroll
    for (int m = 0; m < 4; ++m)
#pragma unroll
        for (int nf = 0; nf < 4; ++nf) {
            int col = wc * 64 + nf * 16 + lr;
#pragma unroll
            for (int reg = 0; reg < 4; ++reg) {
                int row = row0 + wr * 64 + m * 16 + lg * 4 + reg;
                if (row < n) {
                    float v = fmaxf(acc[m][nf][reg], 0.0f);  // relu
                    Cb[(size_t)row * HID + col] = (unsigned short)bfr(v);
                }
            }
        }
}

// Conv gemm: A bf16 (copy-stage), W precast image, out bf16, no bias/relu
__global__ __launch_bounds__(256) void gemm_conv_kernel(const unsigned short* __restrict__ Ab,
                                                        const char* __restrict__ Wimg,
                                                        unsigned short* __restrict__ Cb,
                                                        int n) {
    __shared__ short As[GBM * HID];   // 32 KB
    __shared__ short Ws[HID * HID];   // 32 KB

    int row0 = blockIdx.x * GBM;
    int nrow = min(GBM, n - row0);

    {   // stage A: straight copy with swizzle (16-B chunks keep alignment)
        const uint4* A4 = (const uint4*)(Ab + (size_t)row0 * HID);
        for (int idx = threadIdx.x; idx < GBM * 16; idx += 256) {
            int r = idx >> 4, kc = idx & 15;
            uint4 val = make_uint4(0u, 0u, 0u, 0u);
            if (r < nrow) val = A4[r * 16 + kc];
            int byte = (r * 256 + kc * 16) ^ ((r & 7) << 4);
            *(uint4*)((char*)As + byte) = val;
        }
    }
    {   // stage W: straight 32 KB copy
        const uint4* Wg = (const uint4*)Wimg;
        uint4* Wl = (uint4*)Ws;
        for (int i = threadIdx.x; i < 2048; i += 256) Wl[i] = Wg[i];
    }
    __syncthreads();

    f32x4 acc[4][4];
    gemm_mfma_core(As, Ws, nullptr, acc);

    int wv   = threadIdx.x >> 6;
    int lane = threadIdx.x & 63;
    int wr = wv >> 1, wc = wv & 1;
    int lr = lane & 15, lg = lane >> 4;
#pragma unroll
    for (int m = 0; m < 4; ++m)
#pragma unroll
        for (int nf = 0; nf < 4; ++nf) {
            int col = wc * 64 + nf * 16 + lr;
#pragma unroll
            for (int reg = 0; reg < 4; ++reg) {
                int row = row0 + wr * 64 + m * 16 + lg * 4 + reg;
                if (row < n)
                    Cb[(size_t)row * HID + col] = (unsigned short)bfr(acc[m][nf][reg]);
            }
        }
}

// ---------------------------------------------------------------------------
// CSR aggregation: m is bf16 (halved gather traffic), accumulate f32, out f32.
__global__ __launch_bounds__(128) void agg_csr_kernel(const unsigned short* __restrict__ m,
                                                      const float* __restrict__ wts,
                                                      const float* __restrict__ dinv,
                                                      const float* __restrict__ conv_b,
                                                      const unsigned* __restrict__ rowptr,
                                                      const int* __restrict__ ecol,
                                                      float* __restrict__ out) {
    int v = blockIdx.x;
    int c = threadIdx.x;
    float dv = dinv[v];
    float acc = conv_b[c] + b2f(m[(size_t)v * HID + c]) * dv * dv;
    unsigned i   = rowptr[v];
    unsigned end = rowptr[v + 1];
    for (; i + 1 < end; i += 2) {
        int s0 = ecol[i], s1 = ecol[i + 1];
        float w0 = wts[i], w1 = wts[i + 1];
        acc = fmaf(w0, b2f(m[(size_t)s0 * HID + c]), acc);
        acc = fmaf(w1, b2f(m[(size_t)s1 * HID + c]), acc);
    }
    if (i < end) acc = fmaf(wts[i], b2f(m[(size_t)ecol[i] * HID + c]), acc);
    out[(size_t)v * HID + c] = acc;
}

// ---------------------------------------------------------------------------
__global__ __launch_bounds__(256) void bn_stats_kernel(const float* __restrict__ h,
                                                       float* __restrict__ stats, int n) {
    int c = threadIdx.x & 127;
    int rt = (blockIdx.x * blockDim.x + threadIdx.x) >> 7;
    int rstride = (gridDim.x * blockDim.x) >> 7;
    float s = 0.0f, s2 = 0.0f;
    for (int r = rt; r < n; r += rstride) {
        float v = h[(size_t)r * HID + c];
        s += v; s2 += v * v;
    }
    atomicAdd(&stats[c], s);
    atomicAdd(&stats[HID + c], s2);
}

__global__ __launch_bounds__(256) void bn_apply_kernel(float* __restrict__ h,
                                                       const float* __restrict__ stats,
                                                       const float* __restrict__ gamma,
                                                       const float* __restrict__ beta,
                                                       int n) {
    int gid = blockIdx.x * blockDim.x + threadIdx.x;
    if (gid >= n * HID) return;
    int c = gid & 127;
    float inv_n = 1.0f / (float)n;
    float mean = stats[c] * inv_n;
    float var  = stats[HID + c] * inv_n - mean * mean;
    float sc = gamma[c] * rsqrtf(var + BN_EPS);
    float sh = beta[c] - mean * sc;
    h[gid] = fmaxf(h[gid] * sc + sh, 0.0f);
}

// ---------------------------------------------------------------------------
// final v2 (unchanged; reads f32 hA)
#define FB_ROWS 32
__global__ __launch_bounds__(256) void final_v2_kernel(const float* __restrict__ h,
                                                       const float* __restrict__ lw,
                                                       const float* __restrict__ lb,
                                                       float* __restrict__ out, int n) {
    __shared__ float lws[HID * OUT_DIM];  // 20 KB
    for (int i = threadIdx.x; i < HID * OUT_DIM; i += 256) lws[i] = lw[i];
    __syncthreads();

    int wave = threadIdx.x >> 6;
    int lane = threadIdx.x & 63;
    int rw   = lane >> 3;
    int sub  = lane & 7;
    int r = blockIdx.x * FB_ROWS + wave * 8 + rw;
    if (r >= n) return;

    int c0 = sub * 5;
    float acc[5];
#pragma unroll
    for (int i = 0; i < 5; ++i) acc[i] = lb[c0 + i];

    const float4* hr4 = (const float4*)(h + (size_t)r * HID);
#pragma unroll 4
    for (int k4 = 0; k4 < HID / 4; ++k4) {
        float4 hv = hr4[k4];
        int kb = k4 * 4;
#pragma unroll
        for (int j = 0; j < 4; ++j) {
            float a = (j == 0) ? hv.x : (j == 1) ? hv.y : (j == 2) ? hv.z : hv.w;
            const float* wr2 = &lws[(kb + j) * OUT_DIM + c0];
#pragma unroll
            for (int i = 0; i < 5; ++i) acc[i] = fmaf(a, wr2[i], acc[i]);
        }
    }

    float mx = acc[0];
#pragma unroll
    for (int i = 1; i < 5; ++i) mx = fmaxf(mx, acc[i]);
    for (int off = 4; off; off >>= 1) mx = fmaxf(mx, __shfl_xor(mx, off));

    float s = 0.0f;
#pragma unroll
    for (int i = 0; i < 5; ++i) s += expf(acc[i] - mx);
    for (int off = 4; off; off >>= 1) s += __shfl_xor(s, off);
    float lse = mx + logf(s);

    float* orow = out + (size_t)r * OUT_DIM + c0;
#pragma unroll
    for (int i = 0; i < 5; ++i) orow[i] = acc[i] - lse;
}

// ---------------------------------------------------------------------------
extern "C" void kernel_launch(void* const* d_in, const int* in_sizes, int n_in,
                              void* d_out, int out_size, void* d_ws, size_t ws_size,
                              hipStream_t stream) {
    const float* x         = (const float*)d_in[0];
    const int*   ei        = (const int*)d_in[1];
    const float* log_alpha = (const float*)d_in[2];
    const float* log_beta  = (const float*)d_in[3];
    const float* mlp_w     = (const float*)d_in[4];
    const float* mlp_b     = (const float*)d_in[5];
    const float* conv_w    = (const float*)d_in[6];
    const float* conv_b    = (const float*)d_in[7];
    const float* bn_gamma  = (const float*)d_in[8];
    const float* bn_beta   = (const float*)d_in[9];
    const float* lin_w     = (const float*)d_in[10];
    const float* lin_b     = (const float*)d_in[11];
    float* out = (float*)d_out;

    const int n = N_NODES, E = N_EDGES;
    const int* src = ei;
    const int* dst = ei + E;

    // workspace layout (256B-aligned segments), total ~62 MB
    char* ws = (char*)d_ws;
    size_t off = 0;
    auto alloc = [&](size_t bytes) { char* p = ws + off; off += (bytes + 255) & ~(size_t)255; return p; };
    size_t hbytes = (size_t)n * HID * sizeof(float);          // 25.6 MB
    size_t hbbytes = (size_t)n * HID * sizeof(unsigned short); // 12.8 MB
    float*          hA   = (float*)alloc(hbytes);
    unsigned short* hBb  = (unsigned short*)alloc(hbbytes);
    unsigned short* hCb  = (unsigned short*)alloc(hbbytes);
    unsigned* rowptr = (unsigned*)alloc((size_t)(n + 1) * 4);
    unsigned* deg    = (unsigned*)alloc((size_t)n * 4);       // reused as cursor
    float*    dinv   = (float*)alloc((size_t)n * 4);
    int*      ecol   = (int*)alloc((size_t)E * 4);            // 3.2 MB
    float*    wts    = (float*)alloc((size_t)E * 4);          // 3.2 MB
    float*    stats  = (float*)alloc(512 * sizeof(float));
    unsigned* bsum   = (unsigned*)alloc(256 * 4);
    char*     wbf    = (char*)alloc(6 * 32768);               // 192 KB precast W

    hipMemsetAsync(deg, 0, (size_t)n * 4, stream);
    hipMemsetAsync(stats, 0, 512 * sizeof(float), stream);

    const int B = 256;
    const int nscan = (n + SCAN_CHUNK - 1) / SCAN_CHUNK;   // 49
    count_deg_kernel<<<(E + B - 1) / B, B, 0, stream>>>(dst, deg, E);
    dinv_kernel<<<(n + B - 1) / B, B, 0, stream>>>(deg, dinv, n);
    scan_partial_kernel<<<nscan, B, 0, stream>>>(deg, bsum, n);
    scan_bsums_kernel<<<1, 64, 0, stream>>>(bsum, nscan);
    scan_chunk_kernel<<<nscan, B, 0, stream>>>(deg, bsum, rowptr, n);
    csr_fill_kernel<<<(E + B - 1) / B, B, 0, stream>>>(src, dst, dinv, deg, ecol, wts, E);

    wcast_kernel<<<6, B, 0, stream>>>(mlp_w, conv_w, wbf);
    init_h_kernel<<<(n * HID + B - 1) / B, B, 0, stream>>>(x, log_alpha, log_beta, hA, n);

    int gemm_grid = (n + GBM - 1) / GBM;
    int ngrid = (n * HID + B - 1) / B;

    for (int i = 0; i < 3; ++i) {
        gemm_mlp_kernel<<<gemm_grid, B, 0, stream>>>(hA, wbf + (size_t)(2 * i) * 32768,
                                                     mlp_b + (size_t)i * HID, hBb, n);
        gemm_conv_kernel<<<gemm_grid, B, 0, stream>>>(hBb, wbf + (size_t)(2 * i + 1) * 32768,
                                                      hCb, n);
        agg_csr_kernel<<<n, 128, 0, stream>>>(hCb, wts, dinv, conv_b + (size_t)i * HID,
                                              rowptr, ecol, hA);
        if (i < 2) {
            float* st = stats + (size_t)i * 256;
            bn_stats_kernel<<<512, B, 0, stream>>>(hA, st, n);
            bn_apply_kernel<<<ngrid, B, 0, stream>>>(hA, st, bn_gamma + (size_t)i * HID,
                                                     bn_beta + (size_t)i * HID, n);
        }
    }

    final_v2_kernel<<<(n + FB_ROWS - 1) / FB_ROWS, B, 0, stream>>>(hA, lin_w, lin_b, out, n);
}